// Round 1
// baseline (330.548 us; speedup 1.0000x reference)
//
#include <hip/hip_runtime.h>
#include <stdint.h>

// CausalConv1d: B=4, L=4096, D=2048, K=4, G=8  (per group: 256 in-ch, 256 out-ch)
//   out[b,l,o] = sum_{k,i} x[b, l+k-3, g*256+i] * w[k,i,o],  g = o>>8
//
// R3: 256x256 8-wave deep-phase GEMM (HK/m201-style schedule), replacing the
//     128x128 2-barrier-per-K-step structure (m97-class, ceilinged ~26% MfmaUtil).
//   - grid 512 = 64 Mtiles x 8 Ntiles; Ntile == group => each x element fetched
//     by exactly ONE block; blockIdx&7 == tileN == XCD => wt slice L2-resident.
//   - A (x, fp32->bf16): reg-staged once per 64-ch block with 3-row causal halo
//     into XOR-swizzled LDS; all 4 taps read row-shifted fragments (no re-fetch).
//   - B (wt bf16): global_load_lds(16B), pre-swizzled global source, dbuf/step.
//   - 3 phase-groups per step (32/16/16 MFMA): reads+stage -> bar -> lgkm ->
//     setprio(1) MFMA setprio(0) -> bar. Counted vmcnt(4/0) at step end ONLY.

#define CC_L 4096
#define CC_D 2048

typedef float f32x4 __attribute__((ext_vector_type(4)));
typedef __bf16 bf16x8 __attribute__((ext_vector_type(8)));

static __device__ __forceinline__ unsigned short f2bf(float f) {
    union { float f; uint32_t u; } v; v.f = f;
    uint32_t u = v.u;
    u += 0x7fffu + ((u >> 16) & 1u);   // round-to-nearest-even
    return (unsigned short)(u >> 16);
}

static __device__ __forceinline__ uint32_t pk2(float a, float b) {
    return (uint32_t)f2bf(a) | ((uint32_t)f2bf(b) << 16);
}

static __device__ __forceinline__ void glds16(const void* g, void* l) {
    __builtin_amdgcn_global_load_lds(
        (const __attribute__((address_space(1))) uint32_t*)g,
        (__attribute__((address_space(3))) uint32_t*)l, 16, 0, 0);
}

// ---------------------------------------------------------------------------
// prep: wt[o][kk] = bf16(w[k][ch][o]),  kk = (cb*4 + k)*64 + (ch & 63), cb = ch>>6
// (K-order: 64-ch block major, tap minor -- matches conv's step order s = cb*4+t)
// grid = 4 taps * 32 o-tiles * 2 i-halves = 256 blocks, 256 threads.
__global__ __launch_bounds__(256) void cc_prep_w(const float* __restrict__ w,
                                                 unsigned short* __restrict__ wt) {
    __shared__ unsigned short T[64][136];   // [o_local][i_local]
    const int tid = threadIdx.x;
    const int k  = blockIdx.x >> 6;
    const int ot = (blockIdx.x >> 1) & 31;
    const int ih = blockIdx.x & 1;
    const int o0 = ot << 6;
    const int i0 = ih << 7;

#pragma unroll
    for (int it = 0; it < 8; ++it) {
        int i  = it * 16 + (tid >> 4);          // 0..127
        int oc = (tid & 15) << 2;               // 0..60
        const float4 v = *(const float4*)(w + ((size_t)(k * 256 + i0 + i)) * CC_D + o0 + oc);
        T[oc + 0][i] = f2bf(v.x);
        T[oc + 1][i] = f2bf(v.y);
        T[oc + 2][i] = f2bf(v.z);
        T[oc + 3][i] = f2bf(v.w);
    }
    __syncthreads();
#pragma unroll
    for (int it = 0; it < 4; ++it) {
        int o  = it * 16 + (tid >> 4);          // 0..63
        int ic = (tid & 15) << 3;               // 0..120
        int ch = i0 + ic;
        int kk = ((ch >> 6) << 8) + (k << 6) + (ch & 63);
        *(uint4*)(wt + (size_t)(o0 + o) * 1024 + kk) = *(const uint4*)&T[o][ic];
    }
}

// ---------------------------------------------------------------------------
#define A_BYTES 33280            // 260 rows * 128 B (64 bf16/row), XOR-swizzled
#define B_BYTES 32768            // 256 rows * 128 B
#define LDSA(buf) ((buf) * A_BYTES)
#define LDSB(buf) (2 * A_BYTES + (buf) * B_BYTES)

// stage B(step ss) into buffer bbuf: 4 glds/wave, linear dest, pre-swizzled src
#define ISSUE_B4(bbuf, ss) {                                                    \
    const unsigned short* gsrc_ = wg + (ss) * 64 + (b_q << 3);                  \
    _Pragma("unroll")                                                           \
    for (int j_ = 0; j_ < 4; ++j_) {                                            \
        const int rowb_ = (wv << 5) + (j_ << 3);                                \
        glds16(gsrc_ + (size_t)(rowb_ + b_sub) * 1024,                          \
               (void*)&lds[LDSB(bbuf) + (rowb_ << 7)]);                         \
    }                                                                           \
}

// A slot kk (0..3): rows kk*64 + (tid>>3), 8 ch starting (a_c8*8) of block cbn
#define LOAD_A_SLOT(kk, cbn) {                                                  \
    const int r_  = (kk) * 64 + a_r;                                            \
    const int xr_ = l0 - 3 + r_;                                                \
    const float* p_ = xg + (size_t)xr_ * CC_D + ((cbn) << 6) + (a_c8 << 3);     \
    av[kk][0] = (f32x4){0.f, 0.f, 0.f, 0.f};                                    \
    av[kk][1] = (f32x4){0.f, 0.f, 0.f, 0.f};                                    \
    if (xr_ >= 0) { av[kk][0] = *(const f32x4*)p_;                              \
                    av[kk][1] = *(const f32x4*)(p_ + 4); }                      \
}

// extra rows 256..258 (x rows l0+253..l0+255): wave-0 lanes 0..23 only
#define LOAD_A_EXTRA(cbn) {                                                     \
    if (tid < 24) {                                                             \
        const int xr_ = l0 + 253 + (tid >> 3);                                  \
        const float* p_ = xg + (size_t)xr_ * CC_D + ((cbn) << 6) + (a_c8 << 3); \
        ah[0] = *(const f32x4*)p_;                                              \
        ah[1] = *(const f32x4*)(p_ + 4);                                        \
    }                                                                           \
}

#define WRITE_A_SLOT(kk, dbuf) {                                                \
    const int r_ = (kk) * 64 + a_r;                                             \
    uint4 hv_;                                                                  \
    hv_.x = pk2(av[kk][0][0], av[kk][0][1]);                                    \
    hv_.y = pk2(av[kk][0][2], av[kk][0][3]);                                    \
    hv_.z = pk2(av[kk][1][0], av[kk][1][1]);                                    \
    hv_.w = pk2(av[kk][1][2], av[kk][1][3]);                                    \
    *(uint4*)&lds[LDSA(dbuf) + r_ * 128 + a_sw16] = hv_;                        \
}

#define WRITE_A_EXTRA(dbuf) {                                                   \
    if (tid < 24) {                                                             \
        const int r_ = 256 + (tid >> 3);                                        \
        uint4 hv_;                                                              \
        hv_.x = pk2(ah[0][0], ah[0][1]);                                        \
        hv_.y = pk2(ah[0][2], ah[0][3]);                                        \
        hv_.z = pk2(ah[1][0], ah[1][1]);                                        \
        hv_.w = pk2(ah[1][2], ah[1][3]);                                        \
        *(uint4*)&lds[LDSA(dbuf) + r_ * 128 + a_sw16] = hv_;                    \
    }                                                                           \
}

// A fragment: row = wm + fm*16 + lr + tap, k-granule (ks*4+quad) ^ (row&7)
#define ARD(dst, fm, ks, abuf) {                                                \
    dst = *(const bf16x8*)&lds[LDSA(abuf) + (ar_row + (fm) * 16) * 128 +        \
            (((((ks) << 2) + quad) ^ a_rsw) << 4)];                             \
}
// B fragment: row n = wn + fn*16 + lr
#define BRD(dst, fn, ks, bbuf) {                                                \
    dst = *(const bf16x8*)&lds[LDSB(bbuf) + (b_rowrd + (fn) * 16) * 128 +       \
            (((((ks) << 2) + quad) ^ b_rsw) << 4)];                             \
}

#define MFMA8(fm, x0, x1) {                                                     \
    _Pragma("unroll")                                                           \
    for (int fn_ = 0; fn_ < 4; ++fn_) {                                         \
        acc[fm][fn_] = __builtin_amdgcn_mfma_f32_16x16x32_bf16(                 \
            x0, br[fn_][0], acc[fm][fn_], 0, 0, 0);                             \
        acc[fm][fn_] = __builtin_amdgcn_mfma_f32_16x16x32_bf16(                 \
            x1, br[fn_][1], acc[fm][fn_], 0, 0, 0);                             \
    }                                                                           \
}

#define LGKM0() { asm volatile("s_waitcnt lgkmcnt(0)");                         \
                  __builtin_amdgcn_sched_barrier(0); }
#define SBAR()  __builtin_amdgcn_s_barrier()

// grid = 512 blocks (64 Mtiles x 8 Ntiles), 512 threads (8 waves, 2M x 4N)
__global__ __launch_bounds__(512, 2) void cc_conv(const float* __restrict__ x,
                                                  const unsigned short* __restrict__ wt,
                                                  float* __restrict__ out) {
    __shared__ __align__(16) unsigned char lds[2 * A_BYTES + 2 * B_BYTES]; // 132096

    const int tid   = threadIdx.x;
    const int tileN = blockIdx.x & 7;    // == group == XCD (round-robin dispatch)
    const int tileM = blockIdx.x >> 3;
    const int n0    = tileN << 8;        // out-ch base == in-ch base (cin)
    const int m0    = tileM << 8;
    const int b     = m0 >> 12;          // tiles never span batches (4096%256==0)
    const int l0    = m0 & (CC_L - 1);

    const int lane = tid & 63;
    const int wv   = tid >> 6;
    const int wm   = (wv & 1) << 7;      // 0 / 128
    const int wn   = (wv >> 1) << 6;     // 0 / 64 / 128 / 192
    const int lr   = lane & 15;
    const int quad = lane >> 4;

    // B glds lane constants: linear LDS slot (l>>3 sub-row, l&7 granule) must
    // receive source granule q = (l&7) ^ (row&7)  [swizzle via global addr]
    const int b_sub   = lane >> 3;
    const int b_q     = (lane & 7) ^ b_sub;
    const int b_rowrd = wn + lr;
    const int b_rsw   = lr & 7;

    // A staging lane constants
    const int a_r    = tid >> 3;         // 0..63 base row
    const int a_c8   = tid & 7;          // 16B granule in row
    const int a_sw16 = (a_c8 ^ (a_r & 7)) << 4;

    const float* xg = x + (size_t)b * CC_L * CC_D + n0;
    const unsigned short* wg = wt + (size_t)n0 * 1024;

    f32x4 acc[8][4];
#pragma unroll
    for (int i = 0; i < 8; ++i)
#pragma unroll
        for (int j = 0; j < 4; ++j) acc[i][j] = (f32x4){0.f, 0.f, 0.f, 0.f};

    f32x4 av[4][2];
    f32x4 ah[2];

    // ---- prologue: stage A(cb=0) + B(s=0) into buffers 0 ----
#pragma unroll
    for (int k = 0; k < 4; ++k) LOAD_A_SLOT(k, 0);
    LOAD_A_EXTRA(0);
    ISSUE_B4(0, 0);
    __builtin_amdgcn_sched_barrier(0);
#pragma unroll
    for (int k = 0; k < 4; ++k) WRITE_A_SLOT(k, 0);
    WRITE_A_EXTRA(0);
    asm volatile("s_waitcnt vmcnt(0) lgkmcnt(0)" ::: "memory");
    __builtin_amdgcn_sched_barrier(0);
    SBAR();

    // ---- main loop: step s = cb*4 + t ----
#pragma unroll
    for (int cb = 0; cb < 4; ++cb) {
#pragma unroll
        for (int t = 0; t < 4; ++t) {
            const int s   = cb * 4 + t;
            const int ab  = cb & 1;
            const int bb_ = t & 1;       // == s&1
            const int ar_row = wm + lr + t;
            const int a_rsw  = (lr + t) & 7;
            bf16x8 br[4][2];
            bf16x8 aq[4][2];

            // ===== phase A: fm 0..3 (32 MFMA) =====
            if (s < 15) ISSUE_B4(bb_ ^ 1, s + 1);
            __builtin_amdgcn_sched_barrier(0);     // pin: glds precede A-loads
            if (t == 0 && cb < 3) LOAD_A_EXTRA(cb + 1);
#pragma unroll
            for (int fn = 0; fn < 4; ++fn) {
                BRD(br[fn][0], fn, 0, bb_);
                BRD(br[fn][1], fn, 1, bb_);
            }
#pragma unroll
            for (int fm = 0; fm < 4; ++fm) {
                ARD(aq[fm][0], fm, 0, ab);
                ARD(aq[fm][1], fm, 1, ab);
            }
            SBAR();
            LGKM0();
            __builtin_amdgcn_s_setprio(1);
            MFMA8(0, aq[0][0], aq[0][1]);
            MFMA8(1, aq[1][0], aq[1][1]);
            MFMA8(2, aq[2][0], aq[2][1]);
            MFMA8(3, aq[3][0], aq[3][1]);
            __builtin_amdgcn_s_setprio(0);
            SBAR();

            // ===== phase B: fm 4..5 (16 MFMA) =====
            if (t < 2) { if (cb < 3) LOAD_A_SLOT(2 * t + 0, cb + 1); }
            else       { if (cb < 3) WRITE_A_SLOT(2 * (t - 2) + 0, ab ^ 1); }
            ARD(aq[0][0], 4, 0, ab); ARD(aq[0][1], 4, 1, ab);
            ARD(aq[1][0], 5, 0, ab); ARD(aq[1][1], 5, 1, ab);
            SBAR();
            LGKM0();
            __builtin_amdgcn_s_setprio(1);
            MFMA8(4, aq[0][0], aq[0][1]);
            MFMA8(5, aq[1][0], aq[1][1]);
            __builtin_amdgcn_s_setprio(0);
            SBAR();

            // ===== phase C: fm 6..7 (16 MFMA) + step-end counted wait =====
            if (t < 2) { if (cb < 3) LOAD_A_SLOT(2 * t + 1, cb + 1); }
            else if (cb < 3) {
                WRITE_A_SLOT(2 * (t - 2) + 1, ab ^ 1);
                if (t == 3) WRITE_A_EXTRA(ab ^ 1);
            }
            ARD(aq[0][0], 6, 0, ab); ARD(aq[0][1], 6, 1, ab);
            ARD(aq[1][0], 7, 0, ab); ARD(aq[1][1], 7, 1, ab);
            SBAR();
            LGKM0();
            __builtin_amdgcn_s_setprio(1);
            MFMA8(6, aq[0][0], aq[0][1]);
            MFMA8(7, aq[1][0], aq[1][1]);
            __builtin_amdgcn_s_setprio(0);
            if (s < 15) {
                // B(s+1) glds were issued first in phase A; the only younger
                // vmem ops are this step's A-loads (4) -> vmcnt(4) retires all
                // glds while keeping A-loads in flight. No A-loads: drain.
                if (t < 2 && cb < 3) { asm volatile("s_waitcnt vmcnt(4)" ::: "memory"); }
                else                 { asm volatile("s_waitcnt vmcnt(0)" ::: "memory"); }
                __builtin_amdgcn_sched_barrier(0);
            }
            SBAR();
        }
    }

    // ---- epilogue: C/D layout col = lane&15, row = quad*4 + reg ----
    const size_t obase = (size_t)m0 * CC_D + n0;
#pragma unroll
    for (int fm = 0; fm < 8; ++fm) {
        const int ml = wm + fm * 16 + (quad << 2);
#pragma unroll
        for (int fn = 0; fn < 4; ++fn) {
            const int nl = wn + fn * 16 + lr;
#pragma unroll
            for (int r = 0; r < 4; ++r)
                out[obase + (size_t)(ml + r) * CC_D + nl] = acc[fm][fn][r];
        }
    }
}

extern "C" void kernel_launch(void* const* d_in, const int* in_sizes, int n_in,
                              void* d_out, int out_size, void* d_ws, size_t ws_size,
                              hipStream_t stream) {
    const float* x = (const float*)d_in[0];
    const float* w = (const float*)d_in[1];
    float* out = (float*)d_out;
    unsigned short* wt = (unsigned short*)d_ws;   // 2048*1024 bf16 = 4 MB

    cc_prep_w<<<256, 256, 0, stream>>>(w, wt);
    cc_conv<<<512, 512, 0, stream>>>(x, wt, out);
}

// Round 3
// 273.320 us; speedup vs baseline: 1.2094x; 1.2094x over previous
//
#include <hip/hip_runtime.h>
#include <stdint.h>

// CausalConv1d: B=4, L=4096, D=2048, K=4, G=8  (per group: 256 in-ch, 256 out-ch)
//   out[b,l,o] = sum_{k,i} x[b, l+k-3, g*256+i] * w[k,i,o],  g = o>>8
//
// R5: 256x256 8-wave 4-phase GEMM. R4 raced intermittently; root-cause candidate
//     was counted vmcnt waits relying on in-order retirement across MIXED vmem
//     types (global_load_lds + global_load). R5 removes all counted waits:
//       - full vmcnt(0) drain at every step-end (provably safe; glds are 4
//         phases old by then -> drain ~free; A-loads pay ~1us total).
//       - A-staging clustered at phase-0 boundaries: load slots 0,1 @t1p0;
//         write 0,1 + load 2,3,extra @t2p0; write 2,3,extra @t3p0. Every load
//         has a 4-phase window; every ds_write's data already drained.
//     Register budget ~230 < 256 (8-wave cap): no spill (watch WRITE_SIZE).

#define CC_L 4096
#define CC_D 2048

typedef float f32x4 __attribute__((ext_vector_type(4)));
typedef __bf16 bf16x8 __attribute__((ext_vector_type(8)));

static __device__ __forceinline__ unsigned short f2bf(float f) {
    union { float f; uint32_t u; } v; v.f = f;
    uint32_t u = v.u;
    u += 0x7fffu + ((u >> 16) & 1u);   // round-to-nearest-even
    return (unsigned short)(u >> 16);
}

static __device__ __forceinline__ uint32_t pk2(float a, float b) {
    return (uint32_t)f2bf(a) | ((uint32_t)f2bf(b) << 16);
}

static __device__ __forceinline__ void glds16(const void* g, void* l) {
    __builtin_amdgcn_global_load_lds(
        (const __attribute__((address_space(1))) uint32_t*)g,
        (__attribute__((address_space(3))) uint32_t*)l, 16, 0, 0);
}

// ---------------------------------------------------------------------------
// prep: wt[o][kk] = bf16(w[k][ch][o]),  kk = (cb*4 + k)*64 + (ch & 63), cb = ch>>6
// grid = 4 taps * 32 o-tiles * 2 i-halves = 256 blocks, 256 threads.
__global__ __launch_bounds__(256) void cc_prep_w(const float* __restrict__ w,
                                                 unsigned short* __restrict__ wt) {
    __shared__ unsigned short T[64][136];   // [o_local][i_local]
    const int tid = threadIdx.x;
    const int k  = blockIdx.x >> 6;
    const int ot = (blockIdx.x >> 1) & 31;
    const int ih = blockIdx.x & 1;
    const int o0 = ot << 6;
    const int i0 = ih << 7;

#pragma unroll
    for (int it = 0; it < 8; ++it) {
        int i  = it * 16 + (tid >> 4);          // 0..127
        int oc = (tid & 15) << 2;               // 0..60
        const float4 v = *(const float4*)(w + ((size_t)(k * 256 + i0 + i)) * CC_D + o0 + oc);
        T[oc + 0][i] = f2bf(v.x);
        T[oc + 1][i] = f2bf(v.y);
        T[oc + 2][i] = f2bf(v.z);
        T[oc + 3][i] = f2bf(v.w);
    }
    __syncthreads();
#pragma unroll
    for (int it = 0; it < 4; ++it) {
        int o  = it * 16 + (tid >> 4);          // 0..63
        int ic = (tid & 15) << 3;               // 0..120
        int ch = i0 + ic;
        int kk = ((ch >> 6) << 8) + (k << 6) + (ch & 63);
        *(uint4*)(wt + (size_t)(o0 + o) * 1024 + kk) = *(const uint4*)&T[o][ic];
    }
}

// ---------------------------------------------------------------------------
#define A_BYTES 33280            // 260 rows * 128 B (64 bf16/row), XOR-swizzled
#define B_BYTES 32768            // 256 rows * 128 B
#define LDSA(buf) ((buf) * A_BYTES)
#define LDSB(buf) (2 * A_BYTES + (buf) * B_BYTES)

// stage B(step ss) into buffer bbuf: 4 glds/wave, linear dest, pre-swizzled src
#define ISSUE_B4(bbuf, ss) {                                                    \
    const unsigned short* gsrc_ = wg + (ss) * 64 + (b_q << 3);                  \
    _Pragma("unroll")                                                           \
    for (int j_ = 0; j_ < 4; ++j_) {                                            \
        const int rowb_ = (wv << 5) + (j_ << 3);                                \
        glds16(gsrc_ + (size_t)(rowb_ + b_sub) * 1024,                          \
               (void*)&lds[LDSB(bbuf) + (rowb_ << 7)]);                         \
    }                                                                           \
}

// A slot kk (0..3): rows kk*64 + (tid>>3), 8 ch starting (a_c8*8) of block cbn
#define LOAD_A_SLOT(kk, cbn) {                                                  \
    const int r_  = (kk) * 64 + a_r;                                            \
    const int xr_ = l0 - 3 + r_;                                                \
    const float* p_ = xg + (size_t)xr_ * CC_D + ((cbn) << 6) + (a_c8 << 3);     \
    av[kk][0] = (f32x4){0.f, 0.f, 0.f, 0.f};                                    \
    av[kk][1] = (f32x4){0.f, 0.f, 0.f, 0.f};                                    \
    if (xr_ >= 0) { av[kk][0] = *(const f32x4*)p_;                              \
                    av[kk][1] = *(const f32x4*)(p_ + 4); }                      \
}

// extra rows 256..258 (x rows l0+253..l0+255): wave-0 lanes 0..23 only
#define LOAD_A_EXTRA(cbn) {                                                     \
    if (tid < 24) {                                                             \
        const int xr_ = l0 + 253 + (tid >> 3);                                  \
        const float* p_ = xg + (size_t)xr_ * CC_D + ((cbn) << 6) + (a_c8 << 3); \
        ah[0] = *(const f32x4*)p_;                                              \
        ah[1] = *(const f32x4*)(p_ + 4);                                        \
    }                                                                           \
}

#define WRITE_A_SLOT(kk, dbuf) {                                                \
    const int r_ = (kk) * 64 + a_r;                                             \
    uint4 hv_;                                                                  \
    hv_.x = pk2(av[kk][0][0], av[kk][0][1]);                                    \
    hv_.y = pk2(av[kk][0][2], av[kk][0][3]);                                    \
    hv_.z = pk2(av[kk][1][0], av[kk][1][1]);                                    \
    hv_.w = pk2(av[kk][1][2], av[kk][1][3]);                                    \
    *(uint4*)&lds[LDSA(dbuf) + r_ * 128 + a_sw16] = hv_;                        \
}

#define WRITE_A_EXTRA(dbuf) {                                                   \
    if (tid < 24) {                                                             \
        const int r_ = 256 + (tid >> 3);                                        \
        uint4 hv_;                                                              \
        hv_.x = pk2(ah[0][0], ah[0][1]);                                        \
        hv_.y = pk2(ah[0][2], ah[0][3]);                                        \
        hv_.z = pk2(ah[1][0], ah[1][1]);                                        \
        hv_.w = pk2(ah[1][2], ah[1][3]);                                        \
        *(uint4*)&lds[LDSA(dbuf) + r_ * 128 + a_sw16] = hv_;                    \
    }                                                                           \
}

// A fragment: row = wm + fm*16 + lr + tap, k-granule (ks*4+quad) ^ (row&7)
#define ARD(dst, fm, ks, abuf) {                                                \
    dst = *(const bf16x8*)&lds[LDSA(abuf) + (ar_row + (fm) * 16) * 128 +        \
            (((((ks) << 2) + quad) ^ a_rsw) << 4)];                             \
}
// B fragment: row n = wn + fn*16 + lr
#define BRD(dst, fn, ks, bbuf) {                                                \
    dst = *(const bf16x8*)&lds[LDSB(bbuf) + (b_rowrd + (fn) * 16) * 128 +       \
            (((((ks) << 2) + quad) ^ b_rsw) << 4)];                             \
}

#define MFMA8(fm, x0, x1) {                                                     \
    _Pragma("unroll")                                                           \
    for (int fn_ = 0; fn_ < 4; ++fn_) {                                         \
        acc[fm][fn_] = __builtin_amdgcn_mfma_f32_16x16x32_bf16(                 \
            x0, br[fn_][0], acc[fm][fn_], 0, 0, 0);                             \
        acc[fm][fn_] = __builtin_amdgcn_mfma_f32_16x16x32_bf16(                 \
            x1, br[fn_][1], acc[fm][fn_], 0, 0, 0);                             \
    }                                                                           \
}

#define LGKM0() { asm volatile("s_waitcnt lgkmcnt(0)");                         \
                  __builtin_amdgcn_sched_barrier(0); }
#define SBAR()  __builtin_amdgcn_s_barrier()
#define SCHB()  __builtin_amdgcn_sched_barrier(0)

// grid = 512 blocks (64 Mtiles x 8 Ntiles), 512 threads (8 waves, 2M x 4N)
__global__ __launch_bounds__(512, 2) void cc_conv(const float* __restrict__ x,
                                                  const unsigned short* __restrict__ wt,
                                                  float* __restrict__ out) {
    __shared__ __align__(16) unsigned char lds[2 * A_BYTES + 2 * B_BYTES]; // 132096

    const int tid   = threadIdx.x;
    const int tileN = blockIdx.x & 7;    // == group == XCD (round-robin dispatch)
    const int tileM = blockIdx.x >> 3;
    const int n0    = tileN << 8;        // out-ch base == in-ch base (cin)
    const int m0    = tileM << 8;
    const int b     = m0 >> 12;          // tiles never span batches (4096%256==0)
    const int l0    = m0 & (CC_L - 1);

    const int lane = tid & 63;
    const int wv   = tid >> 6;
    const int wm   = (wv & 1) << 7;      // 0 / 128
    const int wn   = (wv >> 1) << 6;     // 0 / 64 / 128 / 192
    const int lr   = lane & 15;
    const int quad = lane >> 4;

    // B glds lane constants (swizzle via pre-swizzled global source)
    const int b_sub   = lane >> 3;
    const int b_q     = (lane & 7) ^ b_sub;
    const int b_rowrd = wn + lr;
    const int b_rsw   = lr & 7;

    // A staging lane constants
    const int a_r    = tid >> 3;         // 0..63 base row
    const int a_c8   = tid & 7;          // 16B granule in row
    const int a_sw16 = (a_c8 ^ (a_r & 7)) << 4;

    const float* xg = x + (size_t)b * CC_L * CC_D + n0;
    const unsigned short* wg = wt + (size_t)n0 * 1024;

    f32x4 acc[8][4];
#pragma unroll
    for (int i = 0; i < 8; ++i)
#pragma unroll
        for (int j = 0; j < 4; ++j) acc[i][j] = (f32x4){0.f, 0.f, 0.f, 0.f};

    f32x4 av[4][2];
    f32x4 ah[2];

    // ---- prologue: stage A(cb=0) + B(s=0) into buffers 0 ----
#pragma unroll
    for (int k = 0; k < 4; ++k) LOAD_A_SLOT(k, 0);
    LOAD_A_EXTRA(0);
    ISSUE_B4(0, 0);
    SCHB();
#pragma unroll
    for (int k = 0; k < 4; ++k) WRITE_A_SLOT(k, 0);
    WRITE_A_EXTRA(0);
    asm volatile("s_waitcnt vmcnt(0) lgkmcnt(0)" ::: "memory");
    SCHB();
    SBAR();

    // ---- main loop: step s = cb*4 + t, 4 phases x 16 MFMA each ----
#pragma unroll
    for (int cb = 0; cb < 4; ++cb) {
#pragma unroll
        for (int t = 0; t < 4; ++t) {
            const int s   = cb * 4 + t;
            const int ab  = cb & 1;
            const int bb_ = t & 1;       // == s&1
            const int ar_row = wm + lr + t;
            const int a_rsw  = (lr + t) & 7;
            bf16x8 br[4][2];

#pragma unroll
            for (int p = 0; p < 4; ++p) {
                // --- vmem / LDS-write issue, all at phase 0 of each step ---
                if (p == 0) {
                    if (s < 15) { ISSUE_B4(bb_ ^ 1, s + 1); SCHB(); }
                    if (cb < 3) {
                        if (t == 1) {
                            LOAD_A_SLOT(0, cb + 1); LOAD_A_SLOT(1, cb + 1);
                            SCHB();
                        } else if (t == 2) {
                            // writes first (data drained at t1-end): av regs recycle
                            WRITE_A_SLOT(0, ab ^ 1); WRITE_A_SLOT(1, ab ^ 1);
                            LOAD_A_SLOT(2, cb + 1); LOAD_A_SLOT(3, cb + 1);
                            LOAD_A_EXTRA(cb + 1);
                            SCHB();
                        } else if (t == 3) {
                            WRITE_A_SLOT(2, ab ^ 1); WRITE_A_SLOT(3, ab ^ 1);
                            WRITE_A_EXTRA(ab ^ 1);
                            SCHB();
                        }
                    }
                }
                // --- LDS reads for this phase ---
                if (p == 0) {
#pragma unroll
                    for (int fn = 0; fn < 4; ++fn) {
                        BRD(br[fn][0], fn, 0, bb_);
                        BRD(br[fn][1], fn, 1, bb_);
                    }
                }
                bf16x8 aq0[2], aq1[2];
                ARD(aq0[0], 2 * p + 0, 0, ab); ARD(aq0[1], 2 * p + 0, 1, ab);
                ARD(aq1[0], 2 * p + 1, 0, ab); ARD(aq1[1], 2 * p + 1, 1, ab);
                // --- barrier, wait own reads, MFMA cluster ---
                SBAR();
                LGKM0();
                __builtin_amdgcn_s_setprio(1);
                MFMA8(2 * p + 0, aq0[0], aq0[1]);
                MFMA8(2 * p + 1, aq1[0], aq1[1]);
                __builtin_amdgcn_s_setprio(0);
                // --- step-end: FULL drain (no counted waits -- no ordering
                //     assumptions across mixed vmem types; glds are 4 phases
                //     old here so this is cheap) ---
                if (p == 3 && s < 15) {
                    asm volatile("s_waitcnt vmcnt(0)" ::: "memory");
                    SCHB();
                }
                SBAR();
            }
        }
    }

    // ---- epilogue: C/D layout col = lane&15, row = quad*4 + reg ----
    const size_t obase = (size_t)m0 * CC_D + n0;
#pragma unroll
    for (int fm = 0; fm < 8; ++fm) {
        const int ml = wm + fm * 16 + (quad << 2);
#pragma unroll
        for (int fn = 0; fn < 4; ++fn) {
            const int nl = wn + fn * 16 + lr;
#pragma unroll
            for (int r = 0; r < 4; ++r)
                out[obase + (size_t)(ml + r) * CC_D + nl] = acc[fm][fn][r];
        }
    }
}

extern "C" void kernel_launch(void* const* d_in, const int* in_sizes, int n_in,
                              void* d_out, int out_size, void* d_ws, size_t ws_size,
                              hipStream_t stream) {
    const float* x = (const float*)d_in[0];
    const float* w = (const float*)d_in[1];
    float* out = (float*)d_out;
    unsigned short* wt = (unsigned short*)d_ws;   // 2048*1024 bf16 = 4 MB

    cc_prep_w<<<256, 256, 0, stream>>>(w, wt);
    cc_conv<<<512, 512, 0, stream>>>(x, wt, out);
}